// Round 7
// baseline (678.799 us; speedup 1.0000x reference)
//
#include <hip/hip_runtime.h>
#include <hip/hip_cooperative_groups.h>

namespace cg = cooperative_groups;

#define DIM 128
#define NBLK 512   // coop grid: needs 2 blocks/CU, capability 4 => 2x margin
#define NTHR 256

typedef __attribute__((ext_vector_type(4))) _Float16 f16x4;
typedef __attribute__((ext_vector_type(8))) _Float16 f16x8;
typedef __attribute__((ext_vector_type(4))) float f32x4;

// ===========================================================================
// Cooperative mega-kernel: all phases, grid.sync() between them.
// ===========================================================================
__global__ __launch_bounds__(NTHR, 4) void k_all(
    const float* __restrict__ x, const int* __restrict__ src,
    const int* __restrict__ dst, const float* __restrict__ W1l,
    const float* __restrict__ b1, const float* __restrict__ W1r,
    const float* __restrict__ w2l, const float* __restrict__ b2,
    const float* __restrict__ w2r, float* __restrict__ out,
    int* deg, int* __restrict__ rowptr, int* __restrict__ col,
    int* __restrict__ part, _Float16* __restrict__ xh,
    _Float16* __restrict__ Wt, _Float16* __restrict__ aggh,
    float* __restrict__ sbuf, float* __restrict__ tbuf, int n, int E) {
  cg::grid_group grid = cg::this_grid();
  __shared__ int sh[256];
  __shared__ float s_l[64], t_l[64];

  const int tid = threadIdx.x;
  const int gtid = blockIdx.x * NTHR + tid;
  const int gsz = NBLK * NTHR;  // 131072
  const int n4 = n * DIM / 4;
  const int nbk = (n + 255) / 256;  // 196 (<=256)

  // ---- P0: zero deg, x->f16, W transpose->f16 ----
  for (int i = gtid; i < n; i += gsz) deg[i] = 0;
  for (int i = gtid; i < n4; i += gsz) {
    float4 v = ((const float4*)x)[i];
    f16x4 o;
    o.x = (_Float16)v.x; o.y = (_Float16)v.y;
    o.z = (_Float16)v.z; o.w = (_Float16)v.w;
    ((f16x4*)xh)[i] = o;
  }
  for (int idx = gtid; idx < 128 * 256; idx += gsz) {
    int nn = idx >> 8, k = idx & 255;
    float v = (k < 128) ? W1l[(size_t)k * 128 + nn]
                        : W1r[(size_t)(k - 128) * 128 + nn];
    Wt[(size_t)nn * 256 + k] = (_Float16)v;
  }
  grid.sync();

  // ---- P1: degree count ----
  for (int e = gtid; e < E; e += gsz) atomicAdd(&deg[dst[e]], 1);
  grid.sync();

  // ---- P2a: per-256-chunk sums ----
  if (blockIdx.x < nbk) {
    int i = blockIdx.x * 256 + tid;
    sh[tid] = (i < n) ? deg[i] : 0;
    __syncthreads();
    for (int off = 128; off > 0; off >>= 1) {
      if (tid < off) sh[tid] += sh[tid + off];
      __syncthreads();
    }
    if (tid == 0) part[blockIdx.x] = sh[0];
  }
  grid.sync();
  // ---- P2b: block 0 scans partials ----
  if (blockIdx.x == 0) {
    int v = (tid < nbk) ? part[tid] : 0;
    sh[tid] = v;
    __syncthreads();
    for (int off = 1; off < 256; off <<= 1) {
      int u = (tid >= off) ? sh[tid - off] : 0;
      __syncthreads();
      sh[tid] += u;
      __syncthreads();
    }
    if (tid < nbk) part[tid] = sh[tid] - v;
  }
  grid.sync();
  // ---- P2c: local scan + offset -> rowptr; deg becomes cursor ----
  if (blockIdx.x < nbk) {
    int i = blockIdx.x * 256 + tid;
    int v = (i < n) ? deg[i] : 0;
    sh[tid] = v;
    __syncthreads();
    for (int off = 1; off < 256; off <<= 1) {
      int u = (tid >= off) ? sh[tid - off] : 0;
      __syncthreads();
      sh[tid] += u;
      __syncthreads();
    }
    int excl = sh[tid] - v + part[blockIdx.x];
    if (i < n) {
      rowptr[i] = excl;
      deg[i] = excl;  // cursor
    }
    if (i == 0) rowptr[n] = E;
  }
  grid.sync();

  // ---- P3: CSR fill ----
  for (int e = gtid; e < E; e += gsz) {
    int p = atomicAdd(&deg[dst[e]], 1);
    col[p] = src[e];
  }
  grid.sync();

  // ---- P4: aggregate, 16 lanes/node, f16x8 loads, unroll-4 ILP ----
  {
    const f16x8* X8 = (const f16x8*)xh;
    int l16 = tid & 15;
    int slot = gtid >> 4;
    int nslots = gsz >> 4;  // 8192 slots
    for (int node = slot; node < n; node += nslots) {
      int b = rowptr[node], e = rowptr[node + 1];
      float a[8];
#pragma unroll
      for (int j = 0; j < 8; ++j) a[j] = 0.f;
      int i = b;
      for (; i + 4 <= e; i += 4) {
        f16x8 v0 = X8[(size_t)col[i] * 16 + l16];
        f16x8 v1 = X8[(size_t)col[i + 1] * 16 + l16];
        f16x8 v2 = X8[(size_t)col[i + 2] * 16 + l16];
        f16x8 v3 = X8[(size_t)col[i + 3] * 16 + l16];
#pragma unroll
        for (int j = 0; j < 8; ++j)
          a[j] += ((float)v0[j] + (float)v1[j]) + ((float)v2[j] + (float)v3[j]);
      }
      for (; i < e; ++i) {
        f16x8 v0 = X8[(size_t)col[i] * 16 + l16];
#pragma unroll
        for (int j = 0; j < 8; ++j) a[j] += (float)v0[j];
      }
      float inv = 1.0f / (float)max(e - b, 1);
      f16x8 o;
#pragma unroll
      for (int j = 0; j < 8; ++j) o[j] = (_Float16)(a[j] * inv);
      ((f16x8*)aggh)[(size_t)node * 16 + l16] = o;
    }
  }
  grid.sync();

  // ---- P5: MFMA GEMM + fused epilogue ----
  {
    int wv = tid >> 6;
    int lane = tid & 63;
    int q = lane >> 4;
    int l16 = lane & 15;
    int rh = wv & 1;
    int ch = wv >> 1;
    int ntiles = (n + 63) / 64;
    for (int tile = blockIdx.x; tile < ntiles; tile += NBLK) {
      int nb = tile * 64;
      if (tid < 64) { s_l[tid] = 0.f; t_l[tid] = 0.f; }
      __syncthreads();

      f32x4 acc[2][4];
#pragma unroll
      for (int rt = 0; rt < 2; ++rt)
#pragma unroll
        for (int ct = 0; ct < 4; ++ct) acc[rt][ct] = (f32x4){0.f, 0.f, 0.f, 0.f};

      const _Float16* arow0[2];
      const _Float16* arow1[2];
#pragma unroll
      for (int rt = 0; rt < 2; ++rt) {
        int r = nb + rh * 32 + rt * 16 + l16;
        if (r > n - 1) r = n - 1;
        arow0[rt] = aggh + (size_t)r * 128 + q * 8;
        arow1[rt] = xh + (size_t)r * 128 + q * 8;
      }
      const _Float16* bp[4];
#pragma unroll
      for (int ct = 0; ct < 4; ++ct)
        bp[ct] = Wt + (size_t)(ch * 64 + ct * 16 + l16) * 256 + q * 8;

#pragma unroll
      for (int s = 0; s < 8; ++s) {
        f16x8 a[2], b[4];
#pragma unroll
        for (int rt = 0; rt < 2; ++rt)
          a[rt] = (s < 4) ? *(const f16x8*)(arow0[rt] + s * 32)
                          : *(const f16x8*)(arow1[rt] + (s - 4) * 32);
#pragma unroll
        for (int ct = 0; ct < 4; ++ct) b[ct] = *(const f16x8*)(bp[ct] + s * 32);
#pragma unroll
        for (int rt = 0; rt < 2; ++rt)
#pragma unroll
          for (int ct = 0; ct < 4; ++ct)
            acc[rt][ct] = __builtin_amdgcn_mfma_f32_16x16x32_f16(
                a[rt], b[ct], acc[rt][ct], 0, 0, 0);
      }

      float bia[4], wl[4], wr[4];
#pragma unroll
      for (int ct = 0; ct < 4; ++ct) {
        int c = ch * 64 + ct * 16 + l16;
        bia[ct] = b1[c];
        wl[ct] = w2l[c];
        wr[ct] = w2r[c];
      }
#pragma unroll
      for (int rt = 0; rt < 2; ++rt) {
#pragma unroll
        for (int r = 0; r < 4; ++r) {
          float sp = 0.f, tp = 0.f;
#pragma unroll
          for (int ct = 0; ct < 4; ++ct) {
            float h = fmaxf(acc[rt][ct][r] + bia[ct], 0.f);
            sp += h * wl[ct];
            tp += h * wr[ct];
          }
#pragma unroll
          for (int m = 1; m < 16; m <<= 1) {
            sp += __shfl_xor(sp, m, 64);
            tp += __shfl_xor(tp, m, 64);
          }
          if (l16 == 0) {
            int row = rh * 32 + rt * 16 + q * 4 + r;
            atomicAdd(&s_l[row], sp);
            atomicAdd(&t_l[row], tp);
          }
        }
      }
      __syncthreads();
      if (tid < 64 && nb + tid < n) {
        sbuf[nb + tid] = s_l[tid];
        tbuf[nb + tid] = t_l[tid];
      }
      __syncthreads();
    }
  }
  grid.sync();

  // ---- P6: layer-2 scalar gather ----
  {
    int l16 = tid & 15;
    int slot = gtid >> 4;
    int nslots = gsz >> 4;
    float b2v = b2[0];
    for (int node = slot; node < n; node += nslots) {
      int b = rowptr[node], e = rowptr[node + 1];
      float p = 0.f;
      for (int j = b + l16; j < e; j += 16) p += sbuf[col[j]];
#pragma unroll
      for (int m = 1; m < 16; m <<= 1) p += __shfl_xor(p, m, 64);
      if (l16 == 0)
        out[node] = p / (float)max(e - b, 1) + b2v + tbuf[node];
    }
  }
}

// ===========================================================================
// Fallback pipeline (R4/R5-proven structure) — used only if the cooperative
// launch is rejected by the runtime. Deterministic: same math either way.
// ===========================================================================

__global__ __launch_bounds__(256) void k_pre(const float* __restrict__ x,
                                             _Float16* __restrict__ xh, int n4,
                                             int bx,
                                             const int* __restrict__ dst,
                                             int* __restrict__ deg, int E,
                                             int be,
                                             const float* __restrict__ W1l,
                                             const float* __restrict__ W1r,
                                             _Float16* __restrict__ Wt) {
  int bid = blockIdx.x;
  if (bid < bx) {
    int i = bid * 256 + threadIdx.x;
    if (i < n4) {
      float4 v = ((const float4*)x)[i];
      f16x4 o;
      o.x = (_Float16)v.x; o.y = (_Float16)v.y;
      o.z = (_Float16)v.z; o.w = (_Float16)v.w;
      ((f16x4*)xh)[i] = o;
    }
  } else if (bid < bx + be) {
    int e = (bid - bx) * 256 + threadIdx.x;
    if (e < E) atomicAdd(&deg[dst[e]], 1);
  } else {
    int idx = (bid - bx - be) * 256 + threadIdx.x;
    if (idx < 128 * 256) {
      int nn = idx >> 8, k = idx & 255;
      float v = (k < 128) ? W1l[(size_t)k * 128 + nn]
                          : W1r[(size_t)(k - 128) * 128 + nn];
      Wt[(size_t)nn * 256 + k] = (_Float16)v;
    }
  }
}

__global__ __launch_bounds__(256) void k_scan1(const int* __restrict__ deg,
                                               int* __restrict__ part, int n) {
  __shared__ int red[256];
  int t = threadIdx.x;
  int i = blockIdx.x * 256 + t;
  red[t] = (i < n) ? deg[i] : 0;
  __syncthreads();
  for (int off = 128; off > 0; off >>= 1) {
    if (t < off) red[t] += red[t + off];
    __syncthreads();
  }
  if (t == 0) part[blockIdx.x] = red[0];
}

__global__ __launch_bounds__(256) void k_scan23(const int* __restrict__ deg,
                                                const int* __restrict__ part,
                                                int npart,
                                                int* __restrict__ rowptr,
                                                int* __restrict__ cursor,
                                                int n, int E) {
  __shared__ int ps[256];
  __shared__ int ls[256];
  int t = threadIdx.x;
  ps[t] = (t < npart) ? part[t] : 0;
  __syncthreads();
  for (int off = 1; off < 256; off <<= 1) {
    int u = (t >= off) ? ps[t - off] : 0;
    __syncthreads();
    ps[t] += u;
    __syncthreads();
  }
  int blockOff = (blockIdx.x == 0) ? 0 : ps[blockIdx.x - 1];
  int i = blockIdx.x * 256 + t;
  int v = (i < n) ? deg[i] : 0;
  ls[t] = v;
  __syncthreads();
  for (int off = 1; off < 256; off <<= 1) {
    int u = (t >= off) ? ls[t - off] : 0;
    __syncthreads();
    ls[t] += u;
    __syncthreads();
  }
  int excl = ls[t] - v + blockOff;
  if (i < n) {
    rowptr[i] = excl;
    cursor[i] = excl;
  }
  if (i == 0) rowptr[n] = E;
}

__global__ __launch_bounds__(256) void k_fill(const int* __restrict__ src,
                                              const int* __restrict__ dst,
                                              int* __restrict__ cursor,
                                              int* __restrict__ col, int E) {
  int e = blockIdx.x * 256 + threadIdx.x;
  if (e < E) {
    int p = atomicAdd(&cursor[dst[e]], 1);
    col[p] = src[e];
  }
}

// 16 lanes/node, f16x8 loads, unroll-4 (max TLP: 50000 slots)
__global__ __launch_bounds__(256) void k_agg(const _Float16* __restrict__ xh,
                                             const int* __restrict__ rowptr,
                                             const int* __restrict__ col,
                                             _Float16* __restrict__ aggh,
                                             int n) {
  const f16x8* X8 = (const f16x8*)xh;
  int l16 = threadIdx.x & 15;
  int node = (blockIdx.x * 256 + threadIdx.x) >> 4;
  if (node >= n) return;
  int b = rowptr[node], e = rowptr[node + 1];
  float a[8];
#pragma unroll
  for (int j = 0; j < 8; ++j) a[j] = 0.f;
  int i = b;
  for (; i + 4 <= e; i += 4) {
    f16x8 v0 = X8[(size_t)col[i] * 16 + l16];
    f16x8 v1 = X8[(size_t)col[i + 1] * 16 + l16];
    f16x8 v2 = X8[(size_t)col[i + 2] * 16 + l16];
    f16x8 v3 = X8[(size_t)col[i + 3] * 16 + l16];
#pragma unroll
    for (int j = 0; j < 8; ++j)
      a[j] += ((float)v0[j] + (float)v1[j]) + ((float)v2[j] + (float)v3[j]);
  }
  for (; i < e; ++i) {
    f16x8 v0 = X8[(size_t)col[i] * 16 + l16];
#pragma unroll
    for (int j = 0; j < 8; ++j) a[j] += (float)v0[j];
  }
  float inv = 1.0f / (float)max(e - b, 1);
  f16x8 o;
#pragma unroll
  for (int j = 0; j < 8; ++j) o[j] = (_Float16)(a[j] * inv);
  ((f16x8*)aggh)[(size_t)node * 16 + l16] = o;
}

__global__ __launch_bounds__(256) void k_gemm(const _Float16* __restrict__ aggh,
                                              const _Float16* __restrict__ xh,
                                              const _Float16* __restrict__ Wt,
                                              const float* __restrict__ b1,
                                              const float* __restrict__ w2l,
                                              const float* __restrict__ w2r,
                                              float* __restrict__ sbuf,
                                              float* __restrict__ tbuf, int n) {
  __shared__ float s_l[64], t_l[64];
  int tid = threadIdx.x;
  int wv = tid >> 6;
  int lane = tid & 63;
  int q = lane >> 4;
  int l16 = lane & 15;
  int rh = wv & 1;
  int ch = wv >> 1;
  int nb = blockIdx.x * 64;

  if (tid < 64) { s_l[tid] = 0.f; t_l[tid] = 0.f; }
  __syncthreads();

  f32x4 acc[2][4];
#pragma unroll
  for (int rt = 0; rt < 2; ++rt)
#pragma unroll
    for (int ct = 0; ct < 4; ++ct) acc[rt][ct] = (f32x4){0.f, 0.f, 0.f, 0.f};

  const _Float16* arow0[2];
  const _Float16* arow1[2];
#pragma unroll
  for (int rt = 0; rt < 2; ++rt) {
    int r = nb + rh * 32 + rt * 16 + l16;
    if (r > n - 1) r = n - 1;
    arow0[rt] = aggh + (size_t)r * 128 + q * 8;
    arow1[rt] = xh + (size_t)r * 128 + q * 8;
  }
  const _Float16* bp[4];
#pragma unroll
  for (int ct = 0; ct < 4; ++ct)
    bp[ct] = Wt + (size_t)(ch * 64 + ct * 16 + l16) * 256 + q * 8;

#pragma unroll
  for (int s = 0; s < 8; ++s) {
    f16x8 a[2], b[4];
#pragma unroll
    for (int rt = 0; rt < 2; ++rt)
      a[rt] = (s < 4) ? *(const f16x8*)(arow0[rt] + s * 32)
                      : *(const f16x8*)(arow1[rt] + (s - 4) * 32);
#pragma unroll
    for (int ct = 0; ct < 4; ++ct) b[ct] = *(const f16x8*)(bp[ct] + s * 32);
#pragma unroll
    for (int rt = 0; rt < 2; ++rt)
#pragma unroll
      for (int ct = 0; ct < 4; ++ct)
        acc[rt][ct] = __builtin_amdgcn_mfma_f32_16x16x32_f16(
            a[rt], b[ct], acc[rt][ct], 0, 0, 0);
  }

  float bia[4], wl[4], wr[4];
#pragma unroll
  for (int ct = 0; ct < 4; ++ct) {
    int c = ch * 64 + ct * 16 + l16;
    bia[ct] = b1[c];
    wl[ct] = w2l[c];
    wr[ct] = w2r[c];
  }
#pragma unroll
  for (int rt = 0; rt < 2; ++rt) {
#pragma unroll
    for (int r = 0; r < 4; ++r) {
      float sp = 0.f, tp = 0.f;
#pragma unroll
      for (int ct = 0; ct < 4; ++ct) {
        float h = fmaxf(acc[rt][ct][r] + bia[ct], 0.f);
        sp += h * wl[ct];
        tp += h * wr[ct];
      }
#pragma unroll
      for (int m = 1; m < 16; m <<= 1) {
        sp += __shfl_xor(sp, m, 64);
        tp += __shfl_xor(tp, m, 64);
      }
      if (l16 == 0) {
        int row = rh * 32 + rt * 16 + q * 4 + r;
        atomicAdd(&s_l[row], sp);
        atomicAdd(&t_l[row], tp);
      }
    }
  }
  __syncthreads();
  if (tid < 64 && nb + tid < n) {
    sbuf[nb + tid] = s_l[tid];
    tbuf[nb + tid] = t_l[tid];
  }
}

__global__ __launch_bounds__(256) void k_out(const float* __restrict__ s,
                                             const int* __restrict__ rowptr,
                                             const int* __restrict__ col,
                                             const float* __restrict__ t,
                                             const float* __restrict__ b2,
                                             float* __restrict__ out, int n) {
  int l = threadIdx.x & 15;
  int node = blockIdx.x * 16 + (threadIdx.x >> 4);
  if (node >= n) return;
  int b = rowptr[node], e = rowptr[node + 1];
  float p = 0.f;
  for (int j = b + l; j < e; j += 16) p += s[col[j]];
#pragma unroll
  for (int m = 1; m < 16; m <<= 1) p += __shfl_xor(p, m, 64);
  if (l == 0)
    out[node] = p / (float)max(e - b, 1) + b2[0] + t[node];
}

// ---------------------------------------------------------------------------

extern "C" void kernel_launch(void* const* d_in, const int* in_sizes, int n_in,
                              void* d_out, int out_size, void* d_ws,
                              size_t ws_size, hipStream_t stream) {
  const float* x   = (const float*)d_in[0];
  const int*   ei  = (const int*)d_in[1];
  const float* W1l = (const float*)d_in[2];
  const float* b1  = (const float*)d_in[3];
  const float* W1r = (const float*)d_in[4];
  const float* w2l = (const float*)d_in[5];
  const float* b2  = (const float*)d_in[6];
  const float* w2r = (const float*)d_in[7];
  float* out = (float*)d_out;

  int n = in_sizes[0] / DIM;  // 50000
  int E = in_sizes[1] / 2;    // 600000
  const int* src = ei;
  const int* dst = ei + E;

  char* ws = (char*)d_ws;
  size_t off = 0;
  auto take = [&](size_t bytes) -> void* {
    void* p = ws + off;
    off = (off + bytes + 511) & ~(size_t)511;
    return p;
  };
  int*      deg    = (int*)take((size_t)n * 4);
  int*      rowptr = (int*)take((size_t)(n + 1) * 4);
  int*      col    = (int*)take((size_t)E * 4);
  int*      part   = (int*)take(1024);
  _Float16* xh     = (_Float16*)take((size_t)n * DIM * 2);
  _Float16* Wt     = (_Float16*)take((size_t)DIM * 256 * 2);
  _Float16* aggh   = (_Float16*)take((size_t)n * DIM * 2);
  float*    sbuf   = (float*)take((size_t)n * 4);
  float*    tbuf   = (float*)take((size_t)n * 4);
  (void)ws_size; (void)n_in; (void)out_size;

  void* args[] = {&x,    &src,  &dst,    &W1l, &b1,   &W1r, &w2l, &b2,
                  &w2r,  &out,  &deg,    &rowptr, &col, &part, &xh, &Wt,
                  &aggh, &sbuf, &tbuf, &n, &E};
  hipError_t err = hipLaunchCooperativeKernel((const void*)k_all, dim3(NBLK),
                                              dim3(NTHR), args, 0, stream);
  if (err != hipSuccess) {
    // Deterministic fallback: same math via the multi-kernel pipeline.
    hipMemsetAsync(deg, 0, (size_t)n * 4, stream);
    int eb  = (E + 255) / 256;
    int nbk = (n + 255) / 256;
    int n4  = n * DIM / 4;
    int bx  = (n4 + 255) / 256;
    int bw  = (DIM * 256 + 255) / 256;
    k_pre<<<bx + eb + bw, 256, 0, stream>>>(x, xh, n4, bx, dst, deg, E, eb,
                                            W1l, W1r, Wt);
    k_scan1<<<nbk, 256, 0, stream>>>(deg, part, n);
    k_scan23<<<nbk, 256, 0, stream>>>(deg, part, nbk, rowptr, deg, n, E);
    k_fill<<<eb, 256, 0, stream>>>(src, dst, deg, col, E);
    k_agg<<<(n * 16 + 255) / 256, 256, 0, stream>>>(xh, rowptr, col, aggh, n);
    k_gemm<<<(n + 63) / 64, 256, 0, stream>>>(aggh, xh, Wt, b1, w2l, w2r,
                                              sbuf, tbuf, n);
    k_out<<<(n + 15) / 16, 256, 0, stream>>>(sbuf, rowptr, col, tbuf, b2, out,
                                             n);
  }
}

// Round 8
// 200.148 us; speedup vs baseline: 3.3915x; 3.3915x over previous
//
#include <hip/hip_runtime.h>

#define DIM 128

typedef __attribute__((ext_vector_type(4))) _Float16 f16x4;
typedef __attribute__((ext_vector_type(8))) _Float16 f16x8;
typedef __attribute__((ext_vector_type(4))) float f32x4;

// ---------------------------------------------------------------------------
// k_pre: fused degree-count + x->f16 convert + W transpose/convert.
// Block ranges: [0,bx) cvt-x, [bx,bx+be) count, [bx+be,..) cvt-w.
// ---------------------------------------------------------------------------
__global__ __launch_bounds__(256) void k_pre(const float* __restrict__ x,
                                             _Float16* __restrict__ xh, int n4,
                                             int bx,
                                             const int* __restrict__ dst,
                                             int* __restrict__ deg, int E,
                                             int be,
                                             const float* __restrict__ W1l,
                                             const float* __restrict__ W1r,
                                             _Float16* __restrict__ Wt) {
  int bid = blockIdx.x;
  if (bid < bx) {
    int i = bid * 256 + threadIdx.x;
    if (i < n4) {
      float4 v = ((const float4*)x)[i];
      f16x4 o;
      o.x = (_Float16)v.x; o.y = (_Float16)v.y;
      o.z = (_Float16)v.z; o.w = (_Float16)v.w;
      ((f16x4*)xh)[i] = o;
    }
  } else if (bid < bx + be) {
    int e = (bid - bx) * 256 + threadIdx.x;
    if (e < E) atomicAdd(&deg[dst[e]], 1);
  } else {
    int idx = (bid - bx - be) * 256 + threadIdx.x;  // 32768 total
    if (idx < 128 * 256) {
      int nn = idx >> 8, k = idx & 255;
      float v = (k < 128) ? W1l[(size_t)k * 128 + nn]
                          : W1r[(size_t)(k - 128) * 128 + nn];
      Wt[(size_t)nn * 256 + k] = (_Float16)v;
    }
  }
}

// ---------------------------------------------------------------------------
// Scan phase 1: per-256-chunk sums.
// ---------------------------------------------------------------------------
__global__ __launch_bounds__(256) void k_scan1(const int* __restrict__ deg,
                                               int* __restrict__ part, int n) {
  __shared__ int red[256];
  int t = threadIdx.x;
  int i = blockIdx.x * 256 + t;
  red[t] = (i < n) ? deg[i] : 0;
  __syncthreads();
  for (int off = 128; off > 0; off >>= 1) {
    if (t < off) red[t] += red[t + off];
    __syncthreads();
  }
  if (t == 0) part[blockIdx.x] = red[0];
}

// ---------------------------------------------------------------------------
// Scan phase 2+3 fused: every block redundantly scans the <=256 partials,
// takes its own offset, then scans its 256-chunk. cursor aliases deg (each
// thread reads deg[i] before the cursor write; no cross-thread hazard).
// ---------------------------------------------------------------------------
__global__ __launch_bounds__(256) void k_scan23(const int* __restrict__ deg,
                                                const int* __restrict__ part,
                                                int npart,
                                                int* __restrict__ rowptr,
                                                int* __restrict__ cursor,
                                                int n, int E) {
  __shared__ int ps[256];
  __shared__ int ls[256];
  int t = threadIdx.x;
  ps[t] = (t < npart) ? part[t] : 0;
  __syncthreads();
  for (int off = 1; off < 256; off <<= 1) {
    int u = (t >= off) ? ps[t - off] : 0;
    __syncthreads();
    ps[t] += u;
    __syncthreads();
  }
  int blockOff = (blockIdx.x == 0) ? 0 : ps[blockIdx.x - 1];
  int i = blockIdx.x * 256 + t;
  int v = (i < n) ? deg[i] : 0;
  ls[t] = v;
  __syncthreads();
  for (int off = 1; off < 256; off <<= 1) {
    int u = (t >= off) ? ls[t - off] : 0;
    __syncthreads();
    ls[t] += u;
    __syncthreads();
  }
  int excl = ls[t] - v + blockOff;
  if (i < n) {
    rowptr[i] = excl;
    cursor[i] = excl;
  }
  if (i == 0) rowptr[n] = E;
}

__global__ __launch_bounds__(256) void k_fill(const int* __restrict__ src,
                                              const int* __restrict__ dst,
                                              int* __restrict__ cursor,
                                              int* __restrict__ col, int E) {
  int e = blockIdx.x * 256 + threadIdx.x;
  if (e < E) {
    int p = atomicAdd(&cursor[dst[e]], 1);
    col[p] = src[e];
  }
}

// ---------------------------------------------------------------------------
// Layer-1 aggregation: 16 lanes/node, f16x8 (16B) loads, unroll-4.
// 4 nodes per wave, 16 outstanding loads/wave, 50000 concurrent node streams.
// ---------------------------------------------------------------------------
__global__ __launch_bounds__(256) void k_agg(const _Float16* __restrict__ xh,
                                             const int* __restrict__ rowptr,
                                             const int* __restrict__ col,
                                             _Float16* __restrict__ aggh,
                                             int n) {
  const f16x8* X8 = (const f16x8*)xh;
  int l16 = threadIdx.x & 15;
  int node = (blockIdx.x * 256 + threadIdx.x) >> 4;
  if (node >= n) return;
  int b = rowptr[node], e = rowptr[node + 1];
  float a[8];
#pragma unroll
  for (int j = 0; j < 8; ++j) a[j] = 0.f;
  int i = b;
  for (; i + 4 <= e; i += 4) {
    f16x8 v0 = X8[(size_t)col[i] * 16 + l16];
    f16x8 v1 = X8[(size_t)col[i + 1] * 16 + l16];
    f16x8 v2 = X8[(size_t)col[i + 2] * 16 + l16];
    f16x8 v3 = X8[(size_t)col[i + 3] * 16 + l16];
#pragma unroll
    for (int j = 0; j < 8; ++j)
      a[j] += ((float)v0[j] + (float)v1[j]) + ((float)v2[j] + (float)v3[j]);
  }
  for (; i < e; ++i) {
    f16x8 v0 = X8[(size_t)col[i] * 16 + l16];
#pragma unroll
    for (int j = 0; j < 8; ++j) a[j] += (float)v0[j];
  }
  float inv = 1.0f / (float)max(e - b, 1);
  f16x8 o;
#pragma unroll
  for (int j = 0; j < 8; ++j) o[j] = (_Float16)(a[j] * inv);
  ((f16x8*)aggh)[(size_t)node * 16 + l16] = o;
}

// ---------------------------------------------------------------------------
// MFMA f16 GEMM + fused epilogue (h never materialized):
//   h = relu([agg|x] @ [W1l;W1r] + b1);  s = h.w2l;  t = h.w2r
// Block: 64 rows x 128 cols, 4 waves in 2x2 (row-half x col-half).
// Wave: 2 row-tiles x 4 col-tiles, K=256 in 8 steps of mfma 16x16x32.
// ---------------------------------------------------------------------------
__global__ __launch_bounds__(256) void k_gemm(const _Float16* __restrict__ aggh,
                                              const _Float16* __restrict__ xh,
                                              const _Float16* __restrict__ Wt,
                                              const float* __restrict__ b1,
                                              const float* __restrict__ w2l,
                                              const float* __restrict__ w2r,
                                              float* __restrict__ sbuf,
                                              float* __restrict__ tbuf, int n) {
  __shared__ float s_l[64], t_l[64];
  int tid = threadIdx.x;
  int wv = tid >> 6;
  int lane = tid & 63;
  int q = lane >> 4;
  int l16 = lane & 15;
  int rh = wv & 1;
  int ch = wv >> 1;
  int nb = blockIdx.x * 64;

  if (tid < 64) { s_l[tid] = 0.f; t_l[tid] = 0.f; }
  __syncthreads();

  f32x4 acc[2][4];
#pragma unroll
  for (int rt = 0; rt < 2; ++rt)
#pragma unroll
    for (int ct = 0; ct < 4; ++ct) acc[rt][ct] = (f32x4){0.f, 0.f, 0.f, 0.f};

  const _Float16* arow0[2];
  const _Float16* arow1[2];
#pragma unroll
  for (int rt = 0; rt < 2; ++rt) {
    int r = nb + rh * 32 + rt * 16 + l16;
    if (r > n - 1) r = n - 1;  // clamp; stores guarded below
    arow0[rt] = aggh + (size_t)r * 128 + q * 8;
    arow1[rt] = xh + (size_t)r * 128 + q * 8;
  }
  const _Float16* bp[4];
#pragma unroll
  for (int ct = 0; ct < 4; ++ct)
    bp[ct] = Wt + (size_t)(ch * 64 + ct * 16 + l16) * 256 + q * 8;

#pragma unroll
  for (int s = 0; s < 8; ++s) {
    f16x8 a[2], b[4];
#pragma unroll
    for (int rt = 0; rt < 2; ++rt)
      a[rt] = (s < 4) ? *(const f16x8*)(arow0[rt] + s * 32)
                      : *(const f16x8*)(arow1[rt] + (s - 4) * 32);
#pragma unroll
    for (int ct = 0; ct < 4; ++ct) b[ct] = *(const f16x8*)(bp[ct] + s * 32);
#pragma unroll
    for (int rt = 0; rt < 2; ++rt)
#pragma unroll
      for (int ct = 0; ct < 4; ++ct)
        acc[rt][ct] = __builtin_amdgcn_mfma_f32_16x16x32_f16(
            a[rt], b[ct], acc[rt][ct], 0, 0, 0);
  }

  float bia[4], wl[4], wr[4];
#pragma unroll
  for (int ct = 0; ct < 4; ++ct) {
    int c = ch * 64 + ct * 16 + l16;
    bia[ct] = b1[c];
    wl[ct] = w2l[c];
    wr[ct] = w2r[c];
  }
#pragma unroll
  for (int rt = 0; rt < 2; ++rt) {
#pragma unroll
    for (int r = 0; r < 4; ++r) {
      float sp = 0.f, tp = 0.f;
#pragma unroll
      for (int ct = 0; ct < 4; ++ct) {
        float h = fmaxf(acc[rt][ct][r] + bia[ct], 0.f);
        sp += h * wl[ct];
        tp += h * wr[ct];
      }
#pragma unroll
      for (int m = 1; m < 16; m <<= 1) {  // reduce 16 cols within quad
        sp += __shfl_xor(sp, m, 64);
        tp += __shfl_xor(tp, m, 64);
      }
      if (l16 == 0) {
        int row = rh * 32 + rt * 16 + q * 4 + r;
        atomicAdd(&s_l[row], sp);  // col-halves combine here
        atomicAdd(&t_l[row], tp);
      }
    }
  }
  __syncthreads();
  if (tid < 64 && nb + tid < n) {
    sbuf[nb + tid] = s_l[tid];
    tbuf[nb + tid] = t_l[tid];
  }
}

// ---------------------------------------------------------------------------
// Layer-2 via CSR gather, 16 lanes/node (coalesced col reads):
//   out[i] = mean_j s[col[j]] + b2 + t[i]
// ---------------------------------------------------------------------------
__global__ __launch_bounds__(256) void k_out(const float* __restrict__ s,
                                             const int* __restrict__ rowptr,
                                             const int* __restrict__ col,
                                             const float* __restrict__ t,
                                             const float* __restrict__ b2,
                                             float* __restrict__ out, int n) {
  int l = threadIdx.x & 15;
  int node = (blockIdx.x * 256 + threadIdx.x) >> 4;
  if (node >= n) return;
  int b = rowptr[node], e = rowptr[node + 1];
  float p = 0.f;
  for (int j = b + l; j < e; j += 16) p += s[col[j]];
#pragma unroll
  for (int m = 1; m < 16; m <<= 1) p += __shfl_xor(p, m, 64);
  if (l == 0)
    out[node] = p / (float)max(e - b, 1) + b2[0] + t[node];
}

// ---------------------------------------------------------------------------

extern "C" void kernel_launch(void* const* d_in, const int* in_sizes, int n_in,
                              void* d_out, int out_size, void* d_ws,
                              size_t ws_size, hipStream_t stream) {
  const float* x   = (const float*)d_in[0];
  const int*   ei  = (const int*)d_in[1];
  const float* W1l = (const float*)d_in[2];
  const float* b1  = (const float*)d_in[3];
  const float* W1r = (const float*)d_in[4];
  const float* w2l = (const float*)d_in[5];
  const float* b2  = (const float*)d_in[6];
  const float* w2r = (const float*)d_in[7];
  float* out = (float*)d_out;

  int n = in_sizes[0] / DIM;  // 50000
  int E = in_sizes[1] / 2;    // 600000
  const int* src = ei;
  const int* dst = ei + E;

  // workspace carve-out (~31 MB)
  char* ws = (char*)d_ws;
  size_t off = 0;
  auto take = [&](size_t bytes) -> void* {
    void* p = ws + off;
    off = (off + bytes + 511) & ~(size_t)511;
    return p;
  };
  int*      deg    = (int*)take((size_t)n * 4);  // aliased as cursor
  int*      rowptr = (int*)take((size_t)(n + 1) * 4);
  int*      col    = (int*)take((size_t)E * 4);
  int*      part   = (int*)take(1024);
  _Float16* xh     = (_Float16*)take((size_t)n * DIM * 2);
  _Float16* Wt     = (_Float16*)take((size_t)DIM * 256 * 2);
  _Float16* aggh   = (_Float16*)take((size_t)n * DIM * 2);
  float*    sbuf   = (float*)take((size_t)n * 4);
  float*    tbuf   = (float*)take((size_t)n * 4);
  (void)ws_size; (void)n_in; (void)out_size;

  hipMemsetAsync(deg, 0, (size_t)n * 4, stream);

  int eb  = (E + 255) / 256;          // 2344
  int nbk = (n + 255) / 256;          // 196 (<=256 for partial scan)
  int n4  = n * DIM / 4;              // 1,600,000
  int bx  = (n4 + 255) / 256;         // 6250
  int bw  = (DIM * 256 + 255) / 256;  // 128

  k_pre<<<bx + eb + bw, 256, 0, stream>>>(x, xh, n4, bx, dst, deg, E, eb,
                                          W1l, W1r, Wt);
  k_scan1<<<nbk, 256, 0, stream>>>(deg, part, n);
  k_scan23<<<nbk, 256, 0, stream>>>(deg, part, nbk, rowptr, deg, n, E);
  k_fill<<<eb, 256, 0, stream>>>(src, dst, deg, col, E);
  k_agg<<<(n * 16 + 255) / 256, 256, 0, stream>>>(xh, rowptr, col, aggh, n);
  k_gemm<<<(n + 63) / 64, 256, 0, stream>>>(aggh, xh, Wt, b1, w2l, w2r,
                                            sbuf, tbuf, n);
  k_out<<<(n * 16 + 255) / 256, 256, 0, stream>>>(sbuf, rowptr, col, tbuf, b2,
                                                  out, n);
}